// Round 5
// baseline (224.438 us; speedup 1.0000x reference)
//
#include <hip/hip_runtime.h>

// out = A[j]*S + B[j],  j = floor(16*S) clamped to [0,15]
// A[j] = a[j]/Y, B[j] = (cum[j] - a[j]*j/16)/Y
// a[j] = 0.5 + 4.5*sigmoid(u[j]), Y = sum(a)/16, cum[j] = exclusive prefix(a)/16.
//
// Measured history:
//   NT/NT one-shot blocks        : ~70 us   (R0/R4; sched_barrier pin = null)
//   plain loads (any stores)     : ~80 us   (R1/R3; LLC hit path not faster)
//   copy ceiling on this box     : 6.29 TB/s (m13) vs our 3.8 TB/s mixed
// R5 theory: 4096 one-shot blocks = 16 cold-start pipelines per CU; request
// stream collapses at every block boundary. Fix: 1024 persistent blocks,
// grid-stride over chunks, register ping-pong (vA/vB): prefetch chunk t+1's
// 8 NT loads while computing+storing chunk t. No barriers in the loop ->
// counted vmcnt, loads stay in flight across the store phase.

typedef float vf4 __attribute__((ext_vector_type(4)));

#define MSEG 16
#define VPT  8              // float4s per thread per chunk
#define BLK  256
#define NBLOCKS 1024        // 4 blocks/CU, persistent

#define CHUNK (BLK * VPT)   // 2048 float4s per chunk

__device__ __forceinline__ void load_chunk(vf4 (&v)[VPT], const vf4* __restrict__ S4, int base)
{
    #pragma unroll
    for (int k = 0; k < VPT; ++k)
        v[k] = __builtin_nontemporal_load(&S4[base + k * BLK]);
}

__device__ __forceinline__ void compute_store(const vf4 (&v)[VPT], vf4* __restrict__ out4,
                                              int base, const float* sA, const float* sB)
{
    #pragma unroll
    for (int k = 0; k < VPT; ++k) {
        const vf4 s = v[k];
        vf4 r;
        const int jx = min(max((int)(s.x * 16.0f), 0), 15);
        const int jy = min(max((int)(s.y * 16.0f), 0), 15);
        const int jz = min(max((int)(s.z * 16.0f), 0), 15);
        const int jw = min(max((int)(s.w * 16.0f), 0), 15);
        r.x = fmaf(s.x, sA[jx], sB[jx]);
        r.y = fmaf(s.y, sA[jy], sB[jy]);
        r.z = fmaf(s.z, sA[jz], sB[jz]);
        r.w = fmaf(s.w, sA[jw], sB[jw]);
        __builtin_nontemporal_store(r, &out4[base + k * BLK]);
    }
}

__global__ __launch_bounds__(BLK) void mapping_kernel(
    const vf4* __restrict__ S4,
    const float* __restrict__ u,
    vf4* __restrict__ out4,
    int n4)
{
    __shared__ float sA[MSEG];
    __shared__ float sB[MSEG];

    const int tid = threadIdx.x;

    // Lane-parallel table build in wave 0 (shfl prefix sum, once per block).
    if (tid < 64) {
        float a = 0.0f;
        if (tid < MSEG) {
            float sig = 1.0f / (1.0f + expf(-u[tid]));
            a = 0.5f + 4.5f * sig;
        }
        float p = a;
        #pragma unroll
        for (int off = 1; off < MSEG; off <<= 1) {
            float t = __shfl_up(p, off, 64);
            if (tid >= off) p += t;
        }
        float total = __shfl(p, MSEG - 1, 64);
        if (tid < MSEG) {
            float invY = 16.0f / total;
            float cum  = (p - a) * (1.0f / 16.0f);
            sA[tid] = a * invY;
            sB[tid] = (cum - a * ((float)tid * (1.0f / 16.0f))) * invY;
        }
    }
    __syncthreads();   // only barrier in the kernel

    const int nfull  = n4 / CHUNK;          // full chunks (4096 for this shape)
    const int stride = gridDim.x;

    // Remainder elements (none for 32x1024x1024): block 0, guarded per-f4.
    if (blockIdx.x == 0) {
        for (int i = nfull * CHUNK + tid; i < n4; i += BLK) {
            const vf4 s = __builtin_nontemporal_load(&S4[i]);
            vf4 r;
            const int jx = min(max((int)(s.x * 16.0f), 0), 15);
            const int jy = min(max((int)(s.y * 16.0f), 0), 15);
            const int jz = min(max((int)(s.z * 16.0f), 0), 15);
            const int jw = min(max((int)(s.w * 16.0f), 0), 15);
            r.x = fmaf(s.x, sA[jx], sB[jx]);
            r.y = fmaf(s.y, sA[jy], sB[jy]);
            r.z = fmaf(s.z, sA[jz], sB[jz]);
            r.w = fmaf(s.w, sA[jw], sB[jw]);
            __builtin_nontemporal_store(r, &out4[i]);
        }
    }

    int c = blockIdx.x;
    if (c >= nfull) return;

    // Register ping-pong pipeline over full chunks (static indexing only —
    // runtime-indexed vf4 arrays would spill to scratch).
    vf4 vA[VPT], vB[VPT];
    load_chunk(vA, S4, c * CHUNK + tid);

    for (;;) {
        int c1 = c + stride;
        bool more1 = (c1 < nfull);
        if (more1) load_chunk(vB, S4, c1 * CHUNK + tid);       // prefetch t+1
        __builtin_amdgcn_sched_barrier(0);                     // don't sink prefetch
        compute_store(vA, out4, c * CHUNK + tid, sA, sB);      // finish t
        if (!more1) break;

        int c2 = c1 + stride;
        bool more2 = (c2 < nfull);
        if (more2) load_chunk(vA, S4, c2 * CHUNK + tid);
        __builtin_amdgcn_sched_barrier(0);
        compute_store(vB, out4, c1 * CHUNK + tid, sA, sB);
        if (!more2) break;

        c = c2;
    }
}

extern "C" void kernel_launch(void* const* d_in, const int* in_sizes, int n_in,
                              void* d_out, int out_size, void* d_ws, size_t ws_size,
                              hipStream_t stream)
{
    const vf4*  S4 = (const vf4*)d_in[0];        // [32,1024,1024] fp32
    const float* u = (const float*)d_in[1];      // [16] fp32
    // d_in[2] is M == 16, hardcoded.

    vf4* out4 = (vf4*)d_out;
    const int n4 = out_size / 4;                 // 8,388,608 float4s

    const int nchunk = (n4 + CHUNK - 1) / CHUNK;
    const int grid = nchunk < NBLOCKS ? (nchunk > 0 ? nchunk : 1) : NBLOCKS;
    mapping_kernel<<<grid, BLK, 0, stream>>>(S4, u, out4, n4);
}